// Round 4
// baseline (638.799 us; speedup 1.0000x reference)
//
#include <hip/hip_runtime.h>
#include <math.h>
#include <stdint.h>

// TreeLSTM, all-MFMA, LDS-free. Activations stored in MFMA A-fragment order
// as bf16 hi/lo pairs; weights pre-packed in B-fragment order (hi/lo).
// Split GEMM: A*B ~= Ahi*Bhi + Alo*Bhi + Ahi*Blo (fp32-faithful).
// Projection (out = hidden @ Wp + bp) fused into every level's epilogue via
// 16-lane shfl reduction + atomicAdd at the GLOBAL hidden row (row_base+row).
//
// A-frag tile (16 rows x 32 k): element (m,k) -> lane=(m&15)+16*(k>>3), j=k&7.
// Tile pair = hi then lo, 512 uint16 each. tile(rt,kt) at ((rt*KT+kt))*1024.

typedef __attribute__((ext_vector_type(8))) short bf16x8;
typedef __attribute__((ext_vector_type(4))) float f32x4;
typedef __attribute__((ext_vector_type(8))) unsigned short u16x8;

#define NG 5

__device__ __forceinline__ uint16_t f2bf(float f) {
    uint32_t u = __builtin_bit_cast(uint32_t, f);
    u = (u + 0x7fffu + ((u >> 16) & 1u)) >> 16;
    return (uint16_t)u;
}
__device__ __forceinline__ float bf2f(uint16_t h) {
    uint32_t u = ((uint32_t)h) << 16;
    return __builtin_bit_cast(float, u);
}
__device__ __forceinline__ float sigf(float x) { return 1.0f / (1.0f + __expf(-x)); }
__device__ __forceinline__ float tanhfast(float x) {
    x = fminf(fmaxf(x, -15.f), 15.f);
    float e = __expf(2.0f * x);
    return (e - 1.0f) / (e + 1.0f);
}

// ---- emb gather + hi/lo split into A0 (frag order, KT=8) -------------------
__global__ __launch_bounds__(256) void gather_emb(
    const int* __restrict__ tokens, const float* __restrict__ emb,
    uint16_t* __restrict__ A0)
{
    int W = blockIdx.x * 4 + (threadIdx.x >> 6);   // 8192 wave tasks
    int lane = threadIdx.x & 63;
    int rt = W >> 3, kt = W & 7;
    int m = lane & 15, q = lane >> 4;
    int tok = tokens[rt * 16 + m];
    const float* src = emb + (size_t)tok * 256 + kt * 32 + q * 8;
    float4 f0 = *(const float4*)src;
    float4 f1 = *(const float4*)(src + 4);
    float v[8] = {f0.x, f0.y, f0.z, f0.w, f1.x, f1.y, f1.z, f1.w};
    u16x8 hi, lo;
    #pragma unroll
    for (int j = 0; j < 8; ++j) {
        uint16_t h = f2bf(v[j]);
        hi[j] = h;
        lo[j] = f2bf(v[j] - bf2f(h));
    }
    uint16_t* dst = A0 + (size_t)(rt * 8 + kt) * 1024;
    *(u16x8*)(dst + lane * 8) = hi;
    *(u16x8*)(dst + 512 + lane * 8) = lo;
}

// ---- weight pack into B-frag order, split hi/lo ----------------------------
__global__ __launch_bounds__(256) void pack_w_kernel(
    const float* __restrict__ W0, const float* __restrict__ W1, int KT,
    uint16_t* __restrict__ dhi, uint16_t* __restrict__ dlo)
{
    int gid = blockIdx.x * 256 + threadIdx.x;
    int total = 80 * KT * 64;
    if (gid >= total) return;
    int lane = gid & 63;
    int n  = ((gid >> 6) / KT) * 16 + (lane & 15);
    int kt = (gid >> 6) % KT;
    int k0 = kt * 32 + (lane >> 4) * 8;
    u16x8 vh, vl;
    #pragma unroll
    for (int j = 0; j < 8; ++j) {
        int k = k0 + j;
        const float* src = (k < 256) ? (W0 + (size_t)k * 1280)
                                     : (W1 + (size_t)(k - 256) * 1280);
        float v = src[n];
        uint16_t h = f2bf(v);
        vh[j] = h;
        vl[j] = f2bf(v - bf2f(h));
    }
    *(u16x8*)(dhi + (size_t)gid * 8) = vh;
    *(u16x8*)(dlo + (size_t)gid * 8) = vl;
}

// ---- per-row cell + h-write (next-level A-frag) + fused projection ---------
__device__ __forceinline__ void do_row(
    float gi, float fl, float fr, float go, float gu,
    int row, int n, int d, int jn, bool lvl0,
    const float* __restrict__ c_prev, uint16_t* __restrict__ A_out,
    float* __restrict__ c_out, float* __restrict__ out,
    const float* __restrict__ wp, const float* __restrict__ bp,
    int write_next, int l15, int row_base)
{
    bool ok = row < n;
    float h = 0.f;
    if (ok) {
        float cc;
        if (lvl0) {
            cc = sigf(gi) * tanhfast(gu);
        } else {
            float cl = c_prev[(size_t)(2 * row) * 256 + d];
            float cr = c_prev[(size_t)(2 * row + 1) * 256 + d];
            cc = sigf(gi) * tanhfast(gu) + sigf(fl) * cl + sigf(fr) * cr;
        }
        h = sigf(go) * tanhfast(cc);
        if (write_next) {
            c_out[(size_t)row * 256 + d] = cc;
            int nrow = row >> 1;
            int k = (row & 1) * 256 + d;
            int kt = k >> 5, q2 = (k >> 3) & 3, j2 = k & 7;
            int lane2 = (nrow & 15) + 16 * q2;
            size_t base = (size_t)((nrow >> 4) * 16 + kt) * 1024 + lane2 * 8 + j2;
            uint16_t hb = f2bf(h);
            A_out[base] = hb;
            A_out[base + 512] = f2bf(h - bf2f(hb));
        }
    }
    float p[5];
    #pragma unroll
    for (int j = 0; j < 5; ++j) p[j] = h * wp[j];
    #pragma unroll
    for (int msk = 1; msk < 16; msk <<= 1) {
        #pragma unroll
        for (int j = 0; j < 5; ++j) p[j] += __shfl_xor(p[j], msk);
    }
    if (l15 == 0 && ok) {
        #pragma unroll
        for (int j = 0; j < 5; ++j) {
            float add = p[j] + (jn == 0 ? bp[j] : 0.f);
            atomicAdd(&out[(size_t)(row_base + row) * 5 + j], add);
        }
    }
}

// ---- level GEMM: no LDS, direct frag loads, fused cell+proj epilogue -------
template<int KT, int MT, bool LVL0>
__global__ __launch_bounds__(256) void gemm_lvl(
    const uint16_t* __restrict__ A,
    const uint16_t* __restrict__ BH, const uint16_t* __restrict__ BL,
    const float* __restrict__ bvec, const float* __restrict__ c_prev,
    const float* __restrict__ Wp, const float* __restrict__ bp,
    uint16_t* __restrict__ A_out, float* __restrict__ c_out,
    float* __restrict__ out, int n, int write_next, int row_base)
{
    const int tid = threadIdx.x, wave = tid >> 6, lane = tid & 63;
    const int quad = lane >> 4, l15 = lane & 15;
    const int jn = blockIdx.y;
    const int rw0 = (blockIdx.x * 4 + wave) * (16 * MT);
    const int rowtiles = (n + 15) >> 4;

    f32x4 acc[MT][NG] = {};

    #pragma unroll 4
    for (int kt = 0; kt < KT; ++kt) {
        bf16x8 ah[MT], al[MT];
        #pragma unroll
        for (int mt = 0; mt < MT; ++mt) {
            int rt = rw0 / 16 + mt;
            rt = min(rt, rowtiles - 1);
            const uint16_t* at = A + (size_t)(rt * KT + kt) * 1024;
            ah[mt] = *(const bf16x8*)(at + lane * 8);
            al[mt] = *(const bf16x8*)(at + 512 + lane * 8);
        }
        #pragma unroll
        for (int g = 0; g < NG; ++g) {
            const size_t bo = (size_t)((g * 16 + jn) * KT + kt) * 512 + lane * 8;
            bf16x8 bh = *(const bf16x8*)(BH + bo);
            bf16x8 bl = *(const bf16x8*)(BL + bo);
            #pragma unroll
            for (int mt = 0; mt < MT; ++mt) {
                acc[mt][g] = __builtin_amdgcn_mfma_f32_16x16x32_bf16(ah[mt], bh, acc[mt][g], 0, 0, 0);
                acc[mt][g] = __builtin_amdgcn_mfma_f32_16x16x32_bf16(al[mt], bh, acc[mt][g], 0, 0, 0);
                acc[mt][g] = __builtin_amdgcn_mfma_f32_16x16x32_bf16(ah[mt], bl, acc[mt][g], 0, 0, 0);
            }
        }
    }

    const int d = jn * 16 + l15;
    float bg[NG], wp[5];
    #pragma unroll
    for (int g = 0; g < NG; ++g) bg[g] = bvec[g * 256 + d];
    #pragma unroll
    for (int j = 0; j < 5; ++j) wp[j] = Wp[d * 5 + j];

    #pragma unroll
    for (int mt = 0; mt < MT; ++mt) {
        int rb = rw0 + mt * 16 + quad * 4;
        #pragma unroll
        for (int v = 0; v < 4; ++v) {
            do_row(acc[mt][0][v] + bg[0], acc[mt][1][v] + bg[1],
                   acc[mt][2][v] + bg[2], acc[mt][3][v] + bg[3],
                   acc[mt][4][v] + bg[4],
                   rb + v, n, d, jn, LVL0, c_prev, A_out, c_out, out,
                   wp, bp, write_next, l15, row_base);
        }
    }
}

// ---- fused tail: levels 10..14 (n=16,8,4,2,1), one block, 16 waves ---------
__global__ __launch_bounds__(1024) void tail_kernel(
    uint16_t* __restrict__ AP0, uint16_t* __restrict__ AP1,
    const uint16_t* __restrict__ BH, const uint16_t* __restrict__ BL,
    const float* __restrict__ bvec, float* __restrict__ c0, float* __restrict__ c1,
    const float* __restrict__ Wp, const float* __restrict__ bp,
    float* __restrict__ out, int row_base10)
{
    const int tid = threadIdx.x, wave = tid >> 6, lane = tid & 63;
    const int quad = lane >> 4, l15 = lane & 15;
    const int jn = wave;
    const int d = jn * 16 + l15;

    float bg[NG], wp[5];
    #pragma unroll
    for (int g = 0; g < NG; ++g) bg[g] = bvec[g * 256 + d];
    #pragma unroll
    for (int j = 0; j < 5; ++j) wp[j] = Wp[d * 5 + j];

    int row_base = row_base10;
    for (int t = 10; t <= 14; ++t) {
        int n = 16384 >> t;
        const uint16_t* A = (t & 1) ? AP1 : AP0;
        uint16_t* A_out   = (t & 1) ? AP0 : AP1;
        const float* c_prev = (t & 1) ? c0 : c1;
        float* c_out        = (t & 1) ? c1 : c0;
        int write_next = (t < 14);

        f32x4 acc[NG] = {};
        #pragma unroll 4
        for (int kt = 0; kt < 16; ++kt) {
            const uint16_t* at = A + (size_t)kt * 1024;
            bf16x8 ah = *(const bf16x8*)(at + lane * 8);
            bf16x8 al = *(const bf16x8*)(at + 512 + lane * 8);
            #pragma unroll
            for (int g = 0; g < NG; ++g) {
                const size_t bo = (size_t)((g * 16 + jn) * 16 + kt) * 512 + lane * 8;
                bf16x8 bh = *(const bf16x8*)(BH + bo);
                bf16x8 bl = *(const bf16x8*)(BL + bo);
                acc[g] = __builtin_amdgcn_mfma_f32_16x16x32_bf16(ah, bh, acc[g], 0, 0, 0);
                acc[g] = __builtin_amdgcn_mfma_f32_16x16x32_bf16(al, bh, acc[g], 0, 0, 0);
                acc[g] = __builtin_amdgcn_mfma_f32_16x16x32_bf16(ah, bl, acc[g], 0, 0, 0);
            }
        }

        int rb = quad * 4;
        #pragma unroll
        for (int v = 0; v < 4; ++v) {
            do_row(acc[0][v] + bg[0], acc[1][v] + bg[1], acc[2][v] + bg[2],
                   acc[3][v] + bg[3], acc[4][v] + bg[4],
                   rb + v, n, d, jn, false, c_prev, A_out, c_out, out,
                   wp, bp, write_next, l15, row_base);
        }
        row_base += n;
        __threadfence();
        __syncthreads();
    }
}

extern "C" void kernel_launch(void* const* d_in, const int* in_sizes, int n_in,
                              void* d_out, int out_size, void* d_ws, size_t ws_size,
                              hipStream_t stream)
{
    const int*   tokens = (const int*)  d_in[0];
    const float* emb    = (const float*)d_in[1];
    const float* Wx     = (const float*)d_in[2];
    const float* Ul     = (const float*)d_in[3];
    const float* Ur     = (const float*)d_in[4];
    const float* b      = (const float*)d_in[5];
    const float* Wp     = (const float*)d_in[6];
    const float* bp     = (const float*)d_in[7];
    float* out = (float*)d_out;

    // workspace carve (~62.7 MB)
    uint8_t* w = (uint8_t*)d_ws;
    uint16_t* AP0 = (uint16_t*)w;  w += (size_t)1024 * 8  * 1024 * 2;  // 16.78 MB
    uint16_t* AP1 = (uint16_t*)w;  w += (size_t)512  * 16 * 1024 * 2;  // 16.78 MB
    float*    c0  = (float*)w;     w += (size_t)16384 * 256 * 4;       // 16.78 MB
    float*    c1  = (float*)w;     w += (size_t)8192  * 256 * 4;       //  8.39 MB
    uint16_t* BxH = (uint16_t*)w;  w += (size_t)80 * 8  * 512 * 2;
    uint16_t* BxL = (uint16_t*)w;  w += (size_t)80 * 8  * 512 * 2;
    uint16_t* BuH = (uint16_t*)w;  w += (size_t)80 * 16 * 512 * 2;
    uint16_t* BuL = (uint16_t*)w;  w += (size_t)80 * 16 * 512 * 2;

    hipMemsetAsync(out, 0, (size_t)32767 * 5 * sizeof(float), stream);

    gather_emb<<<2048, 256, 0, stream>>>(tokens, emb, AP0);
    pack_w_kernel<<<160, 256, 0, stream>>>(Wx, Wx, 8,  BxH, BxL);
    pack_w_kernel<<<320, 256, 0, stream>>>(Ul, Ur, 16, BuH, BuL);

    int off[16];
    off[0] = 0;
    for (int t = 0; t < 15; ++t) off[t + 1] = off[t] + (16384 >> t);

    // level 0: rows 16384, K=256
    gemm_lvl<8, 2, true><<<dim3(128, 16), 256, 0, stream>>>(
        AP0, BxH, BxL, b, nullptr, Wp, bp, AP1, c0, out, 16384, 1, 0);

    // levels 1..3: MT=2 (BM=128)
    for (int t = 1; t <= 3; ++t) {
        int n = 16384 >> t;
        gemm_lvl<16, 2, false><<<dim3(n / 128, 16), 256, 0, stream>>>(
            (t & 1) ? AP1 : AP0, BuH, BuL, b, (t & 1) ? c0 : c1, Wp, bp,
            (t & 1) ? AP0 : AP1, (t & 1) ? c1 : c0, out, n, 1, off[t]);
    }
    // levels 4..9: MT=1 (BM=64)
    for (int t = 4; t <= 9; ++t) {
        int n = 16384 >> t;
        int gx = (n + 63) / 64;
        gemm_lvl<16, 1, false><<<dim3(gx, 16), 256, 0, stream>>>(
            (t & 1) ? AP1 : AP0, BuH, BuL, b, (t & 1) ? c0 : c1, Wp, bp,
            (t & 1) ? AP0 : AP1, (t & 1) ? c1 : c0, out, n, 1, off[t]);
    }
    // levels 10..14: fused single-block
    tail_kernel<<<1, 1024, 0, stream>>>(AP0, AP1, BuH, BuL, b, c0, c1, Wp, bp, out, off[10]);
}

// Round 5
// 625.802 us; speedup vs baseline: 1.0208x; 1.0208x over previous
//
#include <hip/hip_runtime.h>
#include <math.h>
#include <stdint.h>

// TreeLSTM, all-MFMA, LDS-free. Activations stored in MFMA A-fragment order
// as bf16 hi/lo pairs; weights pre-packed in B-fragment order (hi/lo).
// Split GEMM: A*B ~= Ahi*Bhi + Alo*Bhi + Ahi*Blo (fp32-faithful).
// Projection (out = hidden @ Wp + bp) fused into every level's epilogue via
// 16-lane shfl reduction + atomicAdd at the GLOBAL hidden row (row_base+row).
//
// NOTE (R4 lesson): __threadfence() on gfx950 = agent-scope fence = L2
// writeback/invalidate (~2.5 us each; 80 of them cost 203 us in the tail).
// Single-workgroup cross-wave global communication needs only __syncthreads()
// (one CU, write-through L1, vmcnt drained by the barrier).
//
// A-frag tile (16 rows x 32 k): element (m,k) -> lane=(m&15)+16*(k>>3), j=k&7.
// Tile pair = hi then lo, 512 uint16 each. tile(rt,kt) at ((rt*KT+kt))*1024.

typedef __attribute__((ext_vector_type(8))) short bf16x8;
typedef __attribute__((ext_vector_type(4))) float f32x4;
typedef __attribute__((ext_vector_type(8))) unsigned short u16x8;

#define NG 5

__device__ __forceinline__ uint16_t f2bf(float f) {
    uint32_t u = __builtin_bit_cast(uint32_t, f);
    u = (u + 0x7fffu + ((u >> 16) & 1u)) >> 16;
    return (uint16_t)u;
}
__device__ __forceinline__ float bf2f(uint16_t h) {
    uint32_t u = ((uint32_t)h) << 16;
    return __builtin_bit_cast(float, u);
}
__device__ __forceinline__ float sigf(float x) { return 1.0f / (1.0f + __expf(-x)); }
__device__ __forceinline__ float tanhfast(float x) {
    x = fminf(fmaxf(x, -15.f), 15.f);
    float e = __expf(2.0f * x);
    return (e - 1.0f) / (e + 1.0f);
}

// ---- emb gather + hi/lo split into A0 (frag order, KT=8) -------------------
__global__ __launch_bounds__(256) void gather_emb(
    const int* __restrict__ tokens, const float* __restrict__ emb,
    uint16_t* __restrict__ A0)
{
    int W = blockIdx.x * 4 + (threadIdx.x >> 6);   // 8192 wave tasks
    int lane = threadIdx.x & 63;
    int rt = W >> 3, kt = W & 7;
    int m = lane & 15, q = lane >> 4;
    int tok = tokens[rt * 16 + m];
    const float* src = emb + (size_t)tok * 256 + kt * 32 + q * 8;
    float4 f0 = *(const float4*)src;
    float4 f1 = *(const float4*)(src + 4);
    float v[8] = {f0.x, f0.y, f0.z, f0.w, f1.x, f1.y, f1.z, f1.w};
    u16x8 hi, lo;
    #pragma unroll
    for (int j = 0; j < 8; ++j) {
        uint16_t h = f2bf(v[j]);
        hi[j] = h;
        lo[j] = f2bf(v[j] - bf2f(h));
    }
    uint16_t* dst = A0 + (size_t)(rt * 8 + kt) * 1024;
    *(u16x8*)(dst + lane * 8) = hi;
    *(u16x8*)(dst + 512 + lane * 8) = lo;
}

// ---- weight pack into B-frag order, split hi/lo ----------------------------
__global__ __launch_bounds__(256) void pack_w_kernel(
    const float* __restrict__ W0, const float* __restrict__ W1, int KT,
    uint16_t* __restrict__ dhi, uint16_t* __restrict__ dlo)
{
    int gid = blockIdx.x * 256 + threadIdx.x;
    int total = 80 * KT * 64;
    if (gid >= total) return;
    int lane = gid & 63;
    int n  = ((gid >> 6) / KT) * 16 + (lane & 15);
    int kt = (gid >> 6) % KT;
    int k0 = kt * 32 + (lane >> 4) * 8;
    u16x8 vh, vl;
    #pragma unroll
    for (int j = 0; j < 8; ++j) {
        int k = k0 + j;
        const float* src = (k < 256) ? (W0 + (size_t)k * 1280)
                                     : (W1 + (size_t)(k - 256) * 1280);
        float v = src[n];
        uint16_t h = f2bf(v);
        vh[j] = h;
        vl[j] = f2bf(v - bf2f(h));
    }
    *(u16x8*)(dhi + (size_t)gid * 8) = vh;
    *(u16x8*)(dlo + (size_t)gid * 8) = vl;
}

// ---- per-row cell + h-write (next-level A-frag) + fused projection ---------
__device__ __forceinline__ void do_row(
    float gi, float fl, float fr, float go, float gu,
    int row, int n, int d, int jn, bool lvl0,
    const float* __restrict__ c_prev, uint16_t* __restrict__ A_out,
    float* __restrict__ c_out, float* __restrict__ out,
    const float* __restrict__ wp, const float* __restrict__ bp,
    int write_next, int l15, int row_base)
{
    bool ok = row < n;
    float h = 0.f;
    if (ok) {
        float cc;
        if (lvl0) {
            cc = sigf(gi) * tanhfast(gu);
        } else {
            float cl = c_prev[(size_t)(2 * row) * 256 + d];
            float cr = c_prev[(size_t)(2 * row + 1) * 256 + d];
            cc = sigf(gi) * tanhfast(gu) + sigf(fl) * cl + sigf(fr) * cr;
        }
        h = sigf(go) * tanhfast(cc);
        if (write_next) {
            c_out[(size_t)row * 256 + d] = cc;
            int nrow = row >> 1;
            int k = (row & 1) * 256 + d;
            int kt = k >> 5, q2 = (k >> 3) & 3, j2 = k & 7;
            int lane2 = (nrow & 15) + 16 * q2;
            size_t base = (size_t)((nrow >> 4) * 16 + kt) * 1024 + lane2 * 8 + j2;
            uint16_t hb = f2bf(h);
            A_out[base] = hb;
            A_out[base + 512] = f2bf(h - bf2f(hb));
        }
    }
    float p[5];
    #pragma unroll
    for (int j = 0; j < 5; ++j) p[j] = h * wp[j];
    #pragma unroll
    for (int msk = 1; msk < 16; msk <<= 1) {
        #pragma unroll
        for (int j = 0; j < 5; ++j) p[j] += __shfl_xor(p[j], msk);
    }
    if (l15 == 0 && ok) {
        #pragma unroll
        for (int j = 0; j < 5; ++j) {
            float add = p[j] + (jn == 0 ? bp[j] : 0.f);
            atomicAdd(&out[(size_t)(row_base + row) * 5 + j], add);
        }
    }
}

// ---- level GEMM: no LDS, direct frag loads, fused cell+proj epilogue -------
template<int KT, int MT, bool LVL0>
__global__ __launch_bounds__(256) void gemm_lvl(
    const uint16_t* __restrict__ A,
    const uint16_t* __restrict__ BH, const uint16_t* __restrict__ BL,
    const float* __restrict__ bvec, const float* __restrict__ c_prev,
    const float* __restrict__ Wp, const float* __restrict__ bp,
    uint16_t* __restrict__ A_out, float* __restrict__ c_out,
    float* __restrict__ out, int n, int write_next, int row_base)
{
    const int tid = threadIdx.x, wave = tid >> 6, lane = tid & 63;
    const int quad = lane >> 4, l15 = lane & 15;
    const int jn = blockIdx.y;
    const int rw0 = (blockIdx.x * 4 + wave) * (16 * MT);
    const int rowtiles = (n + 15) >> 4;

    f32x4 acc[MT][NG] = {};

    #pragma unroll 4
    for (int kt = 0; kt < KT; ++kt) {
        bf16x8 ah[MT], al[MT];
        #pragma unroll
        for (int mt = 0; mt < MT; ++mt) {
            int rt = rw0 / 16 + mt;
            rt = min(rt, rowtiles - 1);
            const uint16_t* at = A + (size_t)(rt * KT + kt) * 1024;
            ah[mt] = *(const bf16x8*)(at + lane * 8);
            al[mt] = *(const bf16x8*)(at + 512 + lane * 8);
        }
        #pragma unroll
        for (int g = 0; g < NG; ++g) {
            const size_t bo = (size_t)((g * 16 + jn) * KT + kt) * 512 + lane * 8;
            bf16x8 bh = *(const bf16x8*)(BH + bo);
            bf16x8 bl = *(const bf16x8*)(BL + bo);
            #pragma unroll
            for (int mt = 0; mt < MT; ++mt) {
                acc[mt][g] = __builtin_amdgcn_mfma_f32_16x16x32_bf16(ah[mt], bh, acc[mt][g], 0, 0, 0);
                acc[mt][g] = __builtin_amdgcn_mfma_f32_16x16x32_bf16(al[mt], bh, acc[mt][g], 0, 0, 0);
                acc[mt][g] = __builtin_amdgcn_mfma_f32_16x16x32_bf16(ah[mt], bl, acc[mt][g], 0, 0, 0);
            }
        }
    }

    const int d = jn * 16 + l15;
    float bg[NG], wp[5];
    #pragma unroll
    for (int g = 0; g < NG; ++g) bg[g] = bvec[g * 256 + d];
    #pragma unroll
    for (int j = 0; j < 5; ++j) wp[j] = Wp[d * 5 + j];

    #pragma unroll
    for (int mt = 0; mt < MT; ++mt) {
        int rb = rw0 + mt * 16 + quad * 4;
        #pragma unroll
        for (int v = 0; v < 4; ++v) {
            do_row(acc[mt][0][v] + bg[0], acc[mt][1][v] + bg[1],
                   acc[mt][2][v] + bg[2], acc[mt][3][v] + bg[3],
                   acc[mt][4][v] + bg[4],
                   rb + v, n, d, jn, LVL0, c_prev, A_out, c_out, out,
                   wp, bp, write_next, l15, row_base);
        }
    }
}

// ---- fused tail: levels 10..14 (n=16,8,4,2,1), one block, 16 waves ---------
// Single workgroup: cross-wave A/c round-trip through global is coherent with
// __syncthreads() alone (one CU). NO __threadfence() here (see R4 note).
__global__ __launch_bounds__(1024) void tail_kernel(
    uint16_t* __restrict__ AP0, uint16_t* __restrict__ AP1,
    const uint16_t* __restrict__ BH, const uint16_t* __restrict__ BL,
    const float* __restrict__ bvec, float* __restrict__ c0, float* __restrict__ c1,
    const float* __restrict__ Wp, const float* __restrict__ bp,
    float* __restrict__ out, int row_base10)
{
    const int tid = threadIdx.x, wave = tid >> 6, lane = tid & 63;
    const int quad = lane >> 4, l15 = lane & 15;
    const int jn = wave;
    const int d = jn * 16 + l15;

    float bg[NG], wp[5];
    #pragma unroll
    for (int g = 0; g < NG; ++g) bg[g] = bvec[g * 256 + d];
    #pragma unroll
    for (int j = 0; j < 5; ++j) wp[j] = Wp[d * 5 + j];

    int row_base = row_base10;
    for (int t = 10; t <= 14; ++t) {
        int n = 16384 >> t;
        const uint16_t* A = (t & 1) ? AP1 : AP0;
        uint16_t* A_out   = (t & 1) ? AP0 : AP1;
        const float* c_prev = (t & 1) ? c0 : c1;
        float* c_out        = (t & 1) ? c1 : c0;
        int write_next = (t < 14);

        f32x4 acc[NG] = {};
        #pragma unroll 4
        for (int kt = 0; kt < 16; ++kt) {
            const uint16_t* at = A + (size_t)kt * 1024;
            bf16x8 ah = *(const bf16x8*)(at + lane * 8);
            bf16x8 al = *(const bf16x8*)(at + 512 + lane * 8);
            #pragma unroll
            for (int g = 0; g < NG; ++g) {
                const size_t bo = (size_t)((g * 16 + jn) * 16 + kt) * 512 + lane * 8;
                bf16x8 bh = *(const bf16x8*)(BH + bo);
                bf16x8 bl = *(const bf16x8*)(BL + bo);
                acc[g] = __builtin_amdgcn_mfma_f32_16x16x32_bf16(ah, bh, acc[g], 0, 0, 0);
                acc[g] = __builtin_amdgcn_mfma_f32_16x16x32_bf16(al, bh, acc[g], 0, 0, 0);
                acc[g] = __builtin_amdgcn_mfma_f32_16x16x32_bf16(ah, bl, acc[g], 0, 0, 0);
            }
        }

        int rb = quad * 4;
        #pragma unroll
        for (int v = 0; v < 4; ++v) {
            do_row(acc[0][v] + bg[0], acc[1][v] + bg[1], acc[2][v] + bg[2],
                   acc[3][v] + bg[3], acc[4][v] + bg[4],
                   rb + v, n, d, jn, false, c_prev, A_out, c_out, out,
                   wp, bp, write_next, l15, row_base);
        }
        row_base += n;
        __syncthreads();
    }
}

extern "C" void kernel_launch(void* const* d_in, const int* in_sizes, int n_in,
                              void* d_out, int out_size, void* d_ws, size_t ws_size,
                              hipStream_t stream)
{
    const int*   tokens = (const int*)  d_in[0];
    const float* emb    = (const float*)d_in[1];
    const float* Wx     = (const float*)d_in[2];
    const float* Ul     = (const float*)d_in[3];
    const float* Ur     = (const float*)d_in[4];
    const float* b      = (const float*)d_in[5];
    const float* Wp     = (const float*)d_in[6];
    const float* bp     = (const float*)d_in[7];
    float* out = (float*)d_out;

    // workspace carve (~62.7 MB)
    uint8_t* w = (uint8_t*)d_ws;
    uint16_t* AP0 = (uint16_t*)w;  w += (size_t)1024 * 8  * 1024 * 2;  // 16.78 MB
    uint16_t* AP1 = (uint16_t*)w;  w += (size_t)512  * 16 * 1024 * 2;  // 16.78 MB
    float*    c0  = (float*)w;     w += (size_t)16384 * 256 * 4;       // 16.78 MB
    float*    c1  = (float*)w;     w += (size_t)8192  * 256 * 4;       //  8.39 MB
    uint16_t* BxH = (uint16_t*)w;  w += (size_t)80 * 8  * 512 * 2;
    uint16_t* BxL = (uint16_t*)w;  w += (size_t)80 * 8  * 512 * 2;
    uint16_t* BuH = (uint16_t*)w;  w += (size_t)80 * 16 * 512 * 2;
    uint16_t* BuL = (uint16_t*)w;  w += (size_t)80 * 16 * 512 * 2;

    hipMemsetAsync(out, 0, (size_t)32767 * 5 * sizeof(float), stream);

    gather_emb<<<2048, 256, 0, stream>>>(tokens, emb, AP0);
    pack_w_kernel<<<160, 256, 0, stream>>>(Wx, Wx, 8,  BxH, BxL);
    pack_w_kernel<<<320, 256, 0, stream>>>(Ul, Ur, 16, BuH, BuL);

    int off[16];
    off[0] = 0;
    for (int t = 0; t < 15; ++t) off[t + 1] = off[t] + (16384 >> t);

    // level 0: rows 16384, K=256
    gemm_lvl<8, 2, true><<<dim3(128, 16), 256, 0, stream>>>(
        AP0, BxH, BxL, b, nullptr, Wp, bp, AP1, c0, out, 16384, 1, 0);

    // levels 1..3: MT=2 (BM=128)
    for (int t = 1; t <= 3; ++t) {
        int n = 16384 >> t;
        gemm_lvl<16, 2, false><<<dim3(n / 128, 16), 256, 0, stream>>>(
            (t & 1) ? AP1 : AP0, BuH, BuL, b, (t & 1) ? c0 : c1, Wp, bp,
            (t & 1) ? AP0 : AP1, (t & 1) ? c1 : c0, out, n, 1, off[t]);
    }
    // levels 4..9: MT=1 (BM=64)
    for (int t = 4; t <= 9; ++t) {
        int n = 16384 >> t;
        int gx = (n + 63) / 64;
        gemm_lvl<16, 1, false><<<dim3(gx, 16), 256, 0, stream>>>(
            (t & 1) ? AP1 : AP0, BuH, BuL, b, (t & 1) ? c0 : c1, Wp, bp,
            (t & 1) ? AP0 : AP1, (t & 1) ? c1 : c0, out, n, 1, off[t]);
    }
    // levels 10..14: fused single-block
    tail_kernel<<<1, 1024, 0, stream>>>(AP0, AP1, BuH, BuL, b, c0, c1, Wp, bp, out, off[10]);
}

// Round 6
// 614.955 us; speedup vs baseline: 1.0388x; 1.0176x over previous
//
#include <hip/hip_runtime.h>
#include <math.h>
#include <stdint.h>

// TreeLSTM, all-MFMA, LDS-free. Activations stored in MFMA A-fragment order
// as bf16 hi/lo pairs; weights pre-packed in B-fragment order (hi/lo).
// Split GEMM: A*B ~= Ahi*Bhi + Alo*Bhi + Ahi*Blo (fp32-faithful).
// Projection (out = hidden @ Wp + bp) fused into every level's epilogue via
// 16-lane shfl reduction + atomicAdd at the GLOBAL hidden row (row_base+row).
//
// R5 lesson: a single-workgroup fused tail serializes ~16 MB of weight reads
// through ONE CU (~190 us at ~10 B/cyc/CU). Deep levels now run as regular
// 16-block launches (B streaming spread over 16 CUs, ~6 us/level).
// R4 lesson: __threadfence() (agent scope) costs ~L2-maintenance; avoid.
//
// A-frag tile (16 rows x 32 k): element (m,k) -> lane=(m&15)+16*(k>>3), j=k&7.
// Tile pair = hi then lo, 512 uint16 each. tile(rt,kt) at ((rt*KT+kt))*1024.

typedef __attribute__((ext_vector_type(8))) short bf16x8;
typedef __attribute__((ext_vector_type(4))) float f32x4;
typedef __attribute__((ext_vector_type(8))) unsigned short u16x8;

#define NG 5

__device__ __forceinline__ uint16_t f2bf(float f) {
    uint32_t u = __builtin_bit_cast(uint32_t, f);
    u = (u + 0x7fffu + ((u >> 16) & 1u)) >> 16;
    return (uint16_t)u;
}
__device__ __forceinline__ float bf2f(uint16_t h) {
    uint32_t u = ((uint32_t)h) << 16;
    return __builtin_bit_cast(float, u);
}
__device__ __forceinline__ float sigf(float x) { return 1.0f / (1.0f + __expf(-x)); }
__device__ __forceinline__ float tanhfast(float x) {
    x = fminf(fmaxf(x, -15.f), 15.f);
    float e = __expf(2.0f * x);
    return (e - 1.0f) / (e + 1.0f);
}

// ---- emb gather + hi/lo split into A0 (frag order, KT=8) -------------------
__global__ __launch_bounds__(256) void gather_emb(
    const int* __restrict__ tokens, const float* __restrict__ emb,
    uint16_t* __restrict__ A0)
{
    int W = blockIdx.x * 4 + (threadIdx.x >> 6);   // 8192 wave tasks
    int lane = threadIdx.x & 63;
    int rt = W >> 3, kt = W & 7;
    int m = lane & 15, q = lane >> 4;
    int tok = tokens[rt * 16 + m];
    const float* src = emb + (size_t)tok * 256 + kt * 32 + q * 8;
    float4 f0 = *(const float4*)src;
    float4 f1 = *(const float4*)(src + 4);
    float v[8] = {f0.x, f0.y, f0.z, f0.w, f1.x, f1.y, f1.z, f1.w};
    u16x8 hi, lo;
    #pragma unroll
    for (int j = 0; j < 8; ++j) {
        uint16_t h = f2bf(v[j]);
        hi[j] = h;
        lo[j] = f2bf(v[j] - bf2f(h));
    }
    uint16_t* dst = A0 + (size_t)(rt * 8 + kt) * 1024;
    *(u16x8*)(dst + lane * 8) = hi;
    *(u16x8*)(dst + 512 + lane * 8) = lo;
}

// ---- weight pack into B-frag order, split hi/lo ----------------------------
__global__ __launch_bounds__(256) void pack_w_kernel(
    const float* __restrict__ W0, const float* __restrict__ W1, int KT,
    uint16_t* __restrict__ dhi, uint16_t* __restrict__ dlo)
{
    int gid = blockIdx.x * 256 + threadIdx.x;
    int total = 80 * KT * 64;
    if (gid >= total) return;
    int lane = gid & 63;
    int n  = ((gid >> 6) / KT) * 16 + (lane & 15);
    int kt = (gid >> 6) % KT;
    int k0 = kt * 32 + (lane >> 4) * 8;
    u16x8 vh, vl;
    #pragma unroll
    for (int j = 0; j < 8; ++j) {
        int k = k0 + j;
        const float* src = (k < 256) ? (W0 + (size_t)k * 1280)
                                     : (W1 + (size_t)(k - 256) * 1280);
        float v = src[n];
        uint16_t h = f2bf(v);
        vh[j] = h;
        vl[j] = f2bf(v - bf2f(h));
    }
    *(u16x8*)(dhi + (size_t)gid * 8) = vh;
    *(u16x8*)(dlo + (size_t)gid * 8) = vl;
}

// ---- per-row cell + h-write (next-level A-frag) + fused projection ---------
__device__ __forceinline__ void do_row(
    float gi, float fl, float fr, float go, float gu,
    int row, int n, int d, int jn, bool lvl0,
    const float* __restrict__ c_prev, uint16_t* __restrict__ A_out,
    float* __restrict__ c_out, float* __restrict__ out,
    const float* __restrict__ wp, const float* __restrict__ bp,
    int write_next, int l15, int row_base)
{
    bool ok = row < n;
    float h = 0.f;
    if (ok) {
        float cc;
        if (lvl0) {
            cc = sigf(gi) * tanhfast(gu);
        } else {
            float cl = c_prev[(size_t)(2 * row) * 256 + d];
            float cr = c_prev[(size_t)(2 * row + 1) * 256 + d];
            cc = sigf(gi) * tanhfast(gu) + sigf(fl) * cl + sigf(fr) * cr;
        }
        h = sigf(go) * tanhfast(cc);
        if (write_next) {
            c_out[(size_t)row * 256 + d] = cc;
            int nrow = row >> 1;
            int k = (row & 1) * 256 + d;
            int kt = k >> 5, q2 = (k >> 3) & 3, j2 = k & 7;
            int lane2 = (nrow & 15) + 16 * q2;
            size_t base = (size_t)((nrow >> 4) * 16 + kt) * 1024 + lane2 * 8 + j2;
            uint16_t hb = f2bf(h);
            A_out[base] = hb;
            A_out[base + 512] = f2bf(h - bf2f(hb));
        }
    }
    float p[5];
    #pragma unroll
    for (int j = 0; j < 5; ++j) p[j] = h * wp[j];
    #pragma unroll
    for (int msk = 1; msk < 16; msk <<= 1) {
        #pragma unroll
        for (int j = 0; j < 5; ++j) p[j] += __shfl_xor(p[j], msk);
    }
    if (l15 == 0 && ok) {
        #pragma unroll
        for (int j = 0; j < 5; ++j) {
            float add = p[j] + (jn == 0 ? bp[j] : 0.f);
            atomicAdd(&out[(size_t)(row_base + row) * 5 + j], add);
        }
    }
}

// ---- level GEMM: no LDS, direct frag loads, fused cell+proj epilogue -------
template<int KT, int MT, bool LVL0>
__global__ __launch_bounds__(256) void gemm_lvl(
    const uint16_t* __restrict__ A,
    const uint16_t* __restrict__ BH, const uint16_t* __restrict__ BL,
    const float* __restrict__ bvec, const float* __restrict__ c_prev,
    const float* __restrict__ Wp, const float* __restrict__ bp,
    uint16_t* __restrict__ A_out, float* __restrict__ c_out,
    float* __restrict__ out, int n, int write_next, int row_base)
{
    const int tid = threadIdx.x, wave = tid >> 6, lane = tid & 63;
    const int quad = lane >> 4, l15 = lane & 15;
    const int jn = blockIdx.y;
    const int rw0 = (blockIdx.x * 4 + wave) * (16 * MT);
    const int rowtiles = (n + 15) >> 4;

    f32x4 acc[MT][NG] = {};

    #pragma unroll 2
    for (int kt = 0; kt < KT; ++kt) {
        bf16x8 ah[MT], al[MT];
        #pragma unroll
        for (int mt = 0; mt < MT; ++mt) {
            int rt = rw0 / 16 + mt;
            rt = min(rt, rowtiles - 1);
            const uint16_t* at = A + (size_t)(rt * KT + kt) * 1024;
            ah[mt] = *(const bf16x8*)(at + lane * 8);
            al[mt] = *(const bf16x8*)(at + 512 + lane * 8);
        }
        #pragma unroll
        for (int g = 0; g < NG; ++g) {
            const size_t bo = (size_t)((g * 16 + jn) * KT + kt) * 512 + lane * 8;
            bf16x8 bh = *(const bf16x8*)(BH + bo);
            bf16x8 bl = *(const bf16x8*)(BL + bo);
            #pragma unroll
            for (int mt = 0; mt < MT; ++mt) {
                acc[mt][g] = __builtin_amdgcn_mfma_f32_16x16x32_bf16(ah[mt], bh, acc[mt][g], 0, 0, 0);
                acc[mt][g] = __builtin_amdgcn_mfma_f32_16x16x32_bf16(al[mt], bh, acc[mt][g], 0, 0, 0);
                acc[mt][g] = __builtin_amdgcn_mfma_f32_16x16x32_bf16(ah[mt], bl, acc[mt][g], 0, 0, 0);
            }
        }
    }

    const int d = jn * 16 + l15;
    float bg[NG], wp[5];
    #pragma unroll
    for (int g = 0; g < NG; ++g) bg[g] = bvec[g * 256 + d];
    #pragma unroll
    for (int j = 0; j < 5; ++j) wp[j] = Wp[d * 5 + j];

    #pragma unroll
    for (int mt = 0; mt < MT; ++mt) {
        int rb = rw0 + mt * 16 + quad * 4;
        #pragma unroll
        for (int v = 0; v < 4; ++v) {
            do_row(acc[mt][0][v] + bg[0], acc[mt][1][v] + bg[1],
                   acc[mt][2][v] + bg[2], acc[mt][3][v] + bg[3],
                   acc[mt][4][v] + bg[4],
                   rb + v, n, d, jn, LVL0, c_prev, A_out, c_out, out,
                   wp, bp, write_next, l15, row_base);
        }
    }
}

extern "C" void kernel_launch(void* const* d_in, const int* in_sizes, int n_in,
                              void* d_out, int out_size, void* d_ws, size_t ws_size,
                              hipStream_t stream)
{
    const int*   tokens = (const int*)  d_in[0];
    const float* emb    = (const float*)d_in[1];
    const float* Wx     = (const float*)d_in[2];
    const float* Ul     = (const float*)d_in[3];
    const float* Ur     = (const float*)d_in[4];
    const float* b      = (const float*)d_in[5];
    const float* Wp     = (const float*)d_in[6];
    const float* bp     = (const float*)d_in[7];
    float* out = (float*)d_out;

    // workspace carve (~62.7 MB)
    uint8_t* w = (uint8_t*)d_ws;
    uint16_t* AP0 = (uint16_t*)w;  w += (size_t)1024 * 8  * 1024 * 2;  // 16.78 MB
    uint16_t* AP1 = (uint16_t*)w;  w += (size_t)512  * 16 * 1024 * 2;  // 16.78 MB
    float*    c0  = (float*)w;     w += (size_t)16384 * 256 * 4;       // 16.78 MB
    float*    c1  = (float*)w;     w += (size_t)8192  * 256 * 4;       //  8.39 MB
    uint16_t* BxH = (uint16_t*)w;  w += (size_t)80 * 8  * 512 * 2;
    uint16_t* BxL = (uint16_t*)w;  w += (size_t)80 * 8  * 512 * 2;
    uint16_t* BuH = (uint16_t*)w;  w += (size_t)80 * 16 * 512 * 2;
    uint16_t* BuL = (uint16_t*)w;  w += (size_t)80 * 16 * 512 * 2;

    hipMemsetAsync(out, 0, (size_t)32767 * 5 * sizeof(float), stream);

    gather_emb<<<2048, 256, 0, stream>>>(tokens, emb, AP0);
    pack_w_kernel<<<160, 256, 0, stream>>>(Wx, Wx, 8,  BxH, BxL);
    pack_w_kernel<<<320, 256, 0, stream>>>(Ul, Ur, 16, BuH, BuL);

    int off[16];
    off[0] = 0;
    for (int t = 0; t < 15; ++t) off[t + 1] = off[t] + (16384 >> t);

    // level 0: rows 16384, K=256, BM=256
    gemm_lvl<8, 4, true><<<dim3(64, 16), 256, 0, stream>>>(
        AP0, BxH, BxL, b, nullptr, Wp, bp, AP1, c0, out, 16384, 1, 0);

    for (int t = 1; t <= 14; ++t) {
        int n = 16384 >> t;
        const uint16_t* Ain = (t & 1) ? AP1 : AP0;
        uint16_t* Aout      = (t & 1) ? AP0 : AP1;
        const float* cin    = (t & 1) ? c0 : c1;
        float* cout         = (t & 1) ? c1 : c0;
        int wn = (t < 14) ? 1 : 0;
        if (n >= 2048) {                 // t=1..3: BM=256
            gemm_lvl<16, 4, false><<<dim3(n / 256, 16), 256, 0, stream>>>(
                Ain, BuH, BuL, b, cin, Wp, bp, Aout, cout, out, n, wn, off[t]);
        } else if (n >= 256) {           // t=4..6: BM=128
            gemm_lvl<16, 2, false><<<dim3(n / 128, 16), 256, 0, stream>>>(
                Ain, BuH, BuL, b, cin, Wp, bp, Aout, cout, out, n, wn, off[t]);
        } else {                         // t=7..14: BM=64
            int gx = (n + 63) / 64;
            gemm_lvl<16, 1, false><<<dim3(gx, 16), 256, 0, stream>>>(
                Ain, BuH, BuL, b, cin, Wp, bp, Aout, cout, out, n, wn, off[t]);
        }
    }
}

// Round 7
// 542.657 us; speedup vs baseline: 1.1772x; 1.1332x over previous
//
#include <hip/hip_runtime.h>
#include <math.h>
#include <stdint.h>

// TreeLSTM, all-MFMA, m97-style LDS staging. Activations in MFMA A-fragment
// order as bf16 hi/lo pairs; weights pre-packed in B-fragment order (hi/lo).
// Split GEMM: A*B ~= Ahi*Bhi + Alo*Bhi + Ahi*Blo (fp32-faithful).
// Projection fused into every level's epilogue (16-lane shfl + atomicAdd).
//
// R6 lesson: LDS-free direct VGPR loads ran at ~9 B/cyc/CU (latency-bound,
// MfmaUtil 7%) because every wave re-read B and every jn-block re-read A.
// m97 evidence: global_load_lds + ds_read_b128 sustains ~64-85 B/cyc/CU.
// This round: B staged once per block (4x less), jn-pairs (2x less A),
// k-split kernel for deep levels (B spread over many CUs, not 16).
// R5 lesson: single-workgroup tail serializes B through one CU. R4 lesson:
// __threadfence() = agent-scope L2 maintenance; never in hot path.
//
// A-frag tile (16 rows x 32 k): element (m,k) -> lane=(m&15)+16*(k>>3), j=k&7.
// Tile pair = hi then lo, 512 uint16 each. tile(rt,kt) at (rt*KT+kt)*1024.
// B plane: (nt*KT+kt)*512 uint16 per chunk, frag order lane*8+j.

typedef __attribute__((ext_vector_type(8))) short bf16x8;
typedef __attribute__((ext_vector_type(4))) float f32x4;
typedef __attribute__((ext_vector_type(8))) unsigned short u16x8;

#define NG 5

__device__ __forceinline__ uint16_t f2bf(float f) {
    uint32_t u = __builtin_bit_cast(uint32_t, f);
    u = (u + 0x7fffu + ((u >> 16) & 1u)) >> 16;
    return (uint16_t)u;
}
__device__ __forceinline__ float bf2f(uint16_t h) {
    uint32_t u = ((uint32_t)h) << 16;
    return __builtin_bit_cast(float, u);
}
__device__ __forceinline__ float sigf(float x) { return 1.0f / (1.0f + __expf(-x)); }
__device__ __forceinline__ float tanhfast(float x) {
    x = fminf(fmaxf(x, -15.f), 15.f);
    float e = __expf(2.0f * x);
    return (e - 1.0f) / (e + 1.0f);
}

__device__ __forceinline__ void gld_lds16(const uint16_t* g, uint16_t* l) {
    __builtin_amdgcn_global_load_lds(
        (const __attribute__((address_space(1))) uint32_t*)g,
        (__attribute__((address_space(3))) uint32_t*)l,
        16, 0, 0);
}

// ---- emb gather + hi/lo split into A0 (frag order, KT=8) -------------------
__global__ __launch_bounds__(256) void gather_emb(
    const int* __restrict__ tokens, const float* __restrict__ emb,
    uint16_t* __restrict__ A0)
{
    int W = blockIdx.x * 4 + (threadIdx.x >> 6);   // 8192 wave tasks
    int lane = threadIdx.x & 63;
    int rt = W >> 3, kt = W & 7;
    int m = lane & 15, q = lane >> 4;
    int tok = tokens[rt * 16 + m];
    const float* src = emb + (size_t)tok * 256 + kt * 32 + q * 8;
    float4 f0 = *(const float4*)src;
    float4 f1 = *(const float4*)(src + 4);
    float v[8] = {f0.x, f0.y, f0.z, f0.w, f1.x, f1.y, f1.z, f1.w};
    u16x8 hi, lo;
    #pragma unroll
    for (int j = 0; j < 8; ++j) {
        uint16_t h = f2bf(v[j]);
        hi[j] = h;
        lo[j] = f2bf(v[j] - bf2f(h));
    }
    uint16_t* dst = A0 + (size_t)(rt * 8 + kt) * 1024;
    *(u16x8*)(dst + lane * 8) = hi;
    *(u16x8*)(dst + 512 + lane * 8) = lo;
}

// ---- weight pack into B-frag order, split hi/lo ----------------------------
__global__ __launch_bounds__(256) void pack_w_kernel(
    const float* __restrict__ W0, const float* __restrict__ W1, int KT,
    uint16_t* __restrict__ dhi, uint16_t* __restrict__ dlo)
{
    int gid = blockIdx.x * 256 + threadIdx.x;
    int total = 80 * KT * 64;
    if (gid >= total) return;
    int lane = gid & 63;
    int n  = ((gid >> 6) / KT) * 16 + (lane & 15);
    int kt = (gid >> 6) % KT;
    int k0 = kt * 32 + (lane >> 4) * 8;
    u16x8 vh, vl;
    #pragma unroll
    for (int j = 0; j < 8; ++j) {
        int k = k0 + j;
        const float* src = (k < 256) ? (W0 + (size_t)k * 1280)
                                     : (W1 + (size_t)(k - 256) * 1280);
        float v = src[n];
        uint16_t h = f2bf(v);
        vh[j] = h;
        vl[j] = f2bf(v - bf2f(h));
    }
    *(u16x8*)(dhi + (size_t)gid * 8) = vh;
    *(u16x8*)(dlo + (size_t)gid * 8) = vl;
}

// ---- per-row cell + h-write (next-level A-frag) + fused projection ---------
__device__ __forceinline__ void do_row(
    float gi, float fl, float fr, float go, float gu,
    int row, int n, int d, int jn, bool lvl0,
    const float* __restrict__ c_prev, uint16_t* __restrict__ A_out,
    float* __restrict__ c_out, float* __restrict__ out,
    const float* __restrict__ wp, const float* __restrict__ bp,
    int write_next, int l15, int row_base)
{
    bool ok = row < n;
    float h = 0.f;
    if (ok) {
        float cc;
        if (lvl0) {
            cc = sigf(gi) * tanhfast(gu);
        } else {
            float cl = c_prev[(size_t)(2 * row) * 256 + d];
            float cr = c_prev[(size_t)(2 * row + 1) * 256 + d];
            cc = sigf(gi) * tanhfast(gu) + sigf(fl) * cl + sigf(fr) * cr;
        }
        h = sigf(go) * tanhfast(cc);
        if (write_next) {
            c_out[(size_t)row * 256 + d] = cc;
            int nrow = row >> 1;
            int k = (row & 1) * 256 + d;
            int kt = k >> 5, q2 = (k >> 3) & 3, j2 = k & 7;
            int lane2 = (nrow & 15) + 16 * q2;
            size_t base = (size_t)((nrow >> 4) * 16 + kt) * 1024 + lane2 * 8 + j2;
            uint16_t hb = f2bf(h);
            A_out[base] = hb;
            A_out[base + 512] = f2bf(h - bf2f(hb));
        }
    }
    float p[5];
    #pragma unroll
    for (int j = 0; j < 5; ++j) p[j] = h * wp[j];
    #pragma unroll
    for (int msk = 1; msk < 16; msk <<= 1) {
        #pragma unroll
        for (int j = 0; j < 5; ++j) p[j] += __shfl_xor(p[j], msk);
    }
    if (l15 == 0 && ok) {
        #pragma unroll
        for (int j = 0; j < 5; ++j) {
            float add = p[j] + (jn == 0 ? bp[j] : 0.f);
            atomicAdd(&out[(size_t)(row_base + row) * 5 + j], add);
        }
    }
}

// ---- big-level GEMM (t=0..3): BM=128, jn-pair per block, LDS-staged --------
// grid (n/128, 8). 4 waves; wave w computes rows [w*32, w*32+32) of the tile.
// Per kt: stage A (16 x 1KB chunks) + B (20 x 1KB: 5g x 2jn2 x 2hl) via DMA.
template<int KT, bool LVL0>
__global__ __launch_bounds__(256, 3) void gemm_big(
    const uint16_t* __restrict__ A,
    const uint16_t* __restrict__ BH, const uint16_t* __restrict__ BL,
    const float* __restrict__ bvec, const float* __restrict__ c_prev,
    const float* __restrict__ Wp, const float* __restrict__ bp,
    uint16_t* __restrict__ A_out, float* __restrict__ c_out,
    float* __restrict__ out, int n, int write_next, int row_base)
{
    __shared__ __align__(16) uint16_t lA[16 * 512];   // [rt_local*2+hl][512]
    __shared__ __align__(16) uint16_t lB[20 * 512];   // [g*4+jn2*2+hl][512]

    const int tid = threadIdx.x, wave = tid >> 6, lane = tid & 63;
    const int quad = lane >> 4, l15 = lane & 15;
    const int by = blockIdx.y;           // jn pair: jn = by*2 + jn2
    const int rt0 = blockIdx.x * 8;
    const int rowtiles = (n + 15) >> 4;

    f32x4 acc[2][2][NG] = {};            // [mt][jn2][g]

    for (int kt = 0; kt < KT; ++kt) {
        for (int c = wave; c < 36; c += 4) {
            if (c < 16) {
                int rt = min(rt0 + (c >> 1), rowtiles - 1);
                const uint16_t* src = A + (size_t)(rt * KT + kt) * 1024 + (c & 1) * 512;
                gld_lds16(src + lane * 8, &lA[c * 512]);
            } else {
                int idx = c - 16;
                int g = idx >> 2, jn2 = (idx >> 1) & 1, hl = idx & 1;
                int nt = g * 16 + by * 2 + jn2;
                const uint16_t* src = (hl ? BL : BH) + (size_t)(nt * KT + kt) * 512;
                gld_lds16(src + lane * 8, &lB[idx * 512]);
            }
        }
        __syncthreads();

        bf16x8 ah[2], al[2];
        #pragma unroll
        for (int mt = 0; mt < 2; ++mt) {
            int c0 = (wave * 2 + mt) * 2;
            ah[mt] = *(const bf16x8*)&lA[c0 * 512 + lane * 8];
            al[mt] = *(const bf16x8*)&lA[(c0 + 1) * 512 + lane * 8];
        }
        #pragma unroll
        for (int g = 0; g < NG; ++g) {
            #pragma unroll
            for (int jn2 = 0; jn2 < 2; ++jn2) {
                bf16x8 bh = *(const bf16x8*)&lB[(g * 4 + jn2 * 2 + 0) * 512 + lane * 8];
                bf16x8 bl = *(const bf16x8*)&lB[(g * 4 + jn2 * 2 + 1) * 512 + lane * 8];
                #pragma unroll
                for (int mt = 0; mt < 2; ++mt) {
                    acc[mt][jn2][g] = __builtin_amdgcn_mfma_f32_16x16x32_bf16(ah[mt], bh, acc[mt][jn2][g], 0, 0, 0);
                    acc[mt][jn2][g] = __builtin_amdgcn_mfma_f32_16x16x32_bf16(al[mt], bh, acc[mt][jn2][g], 0, 0, 0);
                    acc[mt][jn2][g] = __builtin_amdgcn_mfma_f32_16x16x32_bf16(ah[mt], bl, acc[mt][jn2][g], 0, 0, 0);
                }
            }
        }
        __syncthreads();
    }

    const int rw0 = blockIdx.x * 128 + wave * 32;
    #pragma unroll
    for (int jn2 = 0; jn2 < 2; ++jn2) {
        int jn = by * 2 + jn2;
        int d = jn * 16 + l15;
        float bg[NG], wp[5];
        #pragma unroll
        for (int g = 0; g < NG; ++g) bg[g] = bvec[g * 256 + d];
        #pragma unroll
        for (int j = 0; j < 5; ++j) wp[j] = Wp[d * 5 + j];
        #pragma unroll
        for (int mt = 0; mt < 2; ++mt) {
            int rb = rw0 + mt * 16 + quad * 4;
            #pragma unroll
            for (int v = 0; v < 4; ++v) {
                do_row(acc[mt][jn2][0][v] + bg[0], acc[mt][jn2][1][v] + bg[1],
                       acc[mt][jn2][2][v] + bg[2], acc[mt][jn2][3][v] + bg[3],
                       acc[mt][jn2][4][v] + bg[4],
                       rb + v, n, d, jn, LVL0, c_prev, A_out, c_out, out,
                       wp, bp, write_next, l15, row_base);
            }
        }
    }
}

// ---- deep-level GEMM (t=4..14): BM=32, k split across the 4 waves ----------
// grid (ceil(n/32), 16). Wave w handles kt = s*4+w, s=0..3 (K=512, KT=16).
// Each wave DMA-stages its own 14KB slot (A 4 + B 10 chunks); LDS reduction;
// wave 0 does the fused epilogue.
__global__ __launch_bounds__(256, 2) void gemm_ksplit(
    const uint16_t* __restrict__ A,
    const uint16_t* __restrict__ BH, const uint16_t* __restrict__ BL,
    const float* __restrict__ bvec, const float* __restrict__ c_prev,
    const float* __restrict__ Wp, const float* __restrict__ bp,
    uint16_t* __restrict__ A_out, float* __restrict__ c_out,
    float* __restrict__ out, int n, int write_next, int row_base)
{
    __shared__ __align__(16) uint16_t lds[4 * 14 * 512];   // 56 KB

    const int tid = threadIdx.x, wave = tid >> 6, lane = tid & 63;
    const int quad = lane >> 4, l15 = lane & 15;
    const int jn = blockIdx.y;
    const int rt0 = blockIdx.x * 2;
    const int rowtiles = (n + 15) >> 4;

    f32x4 acc[2][NG] = {};
    uint16_t* slot = lds + wave * 14 * 512;

    for (int s = 0; s < 4; ++s) {
        int kt = s * 4 + wave;
        #pragma unroll
        for (int c = 0; c < 14; ++c) {
            if (c < 4) {
                int rt = min(rt0 + (c >> 1), rowtiles - 1);
                const uint16_t* src = A + (size_t)(rt * 16 + kt) * 1024 + (c & 1) * 512;
                gld_lds16(src + lane * 8, &slot[c * 512]);
            } else {
                int idx = c - 4;
                int g = idx >> 1, hl = idx & 1;
                int nt = g * 16 + jn;
                const uint16_t* src = (hl ? BL : BH) + (size_t)(nt * 16 + kt) * 512;
                gld_lds16(src + lane * 8, &slot[c * 512]);
            }
        }
        __syncthreads();

        bf16x8 ah[2], al[2];
        #pragma unroll
        for (int mt = 0; mt < 2; ++mt) {
            ah[mt] = *(const bf16x8*)&slot[(mt * 2 + 0) * 512 + lane * 8];
            al[mt] = *(const bf16x8*)&slot[(mt * 2 + 1) * 512 + lane * 8];
        }
        #pragma unroll
        for (int g = 0; g < NG; ++g) {
            bf16x8 bh = *(const bf16x8*)&slot[(4 + g * 2 + 0) * 512 + lane * 8];
            bf16x8 bl = *(const bf16x8*)&slot[(4 + g * 2 + 1) * 512 + lane * 8];
            #pragma unroll
            for (int mt = 0; mt < 2; ++mt) {
                acc[mt][g] = __builtin_amdgcn_mfma_f32_16x16x32_bf16(ah[mt], bh, acc[mt][g], 0, 0, 0);
                acc[mt][g] = __builtin_amdgcn_mfma_f32_16x16x32_bf16(al[mt], bh, acc[mt][g], 0, 0, 0);
                acc[mt][g] = __builtin_amdgcn_mfma_f32_16x16x32_bf16(ah[mt], bl, acc[mt][g], 0, 0, 0);
            }
        }
        __syncthreads();
    }

    // cross-wave reduction into wave 0
    float* red = (float*)lds;
    float* accf = (float*)acc;                       // 40 floats per lane
    if (wave > 0) {
        #pragma unroll
        for (int i = 0; i < 40; ++i)
            red[((wave - 1) * 40 + i) * 64 + lane] = accf[i];
    }
    __syncthreads();
    if (wave == 0) {
        #pragma unroll
        for (int w = 0; w < 3; ++w)
            #pragma unroll
            for (int i = 0; i < 40; ++i)
                accf[i] += red[(w * 40 + i) * 64 + lane];

        int d = jn * 16 + l15;
        float bg[NG], wp[5];
        #pragma unroll
        for (int g = 0; g < NG; ++g) bg[g] = bvec[g * 256 + d];
        #pragma unroll
        for (int j = 0; j < 5; ++j) wp[j] = Wp[d * 5 + j];
        #pragma unroll
        for (int mt = 0; mt < 2; ++mt) {
            int rb = blockIdx.x * 32 + mt * 16 + quad * 4;
            #pragma unroll
            for (int v = 0; v < 4; ++v) {
                do_row(acc[mt][0][v] + bg[0], acc[mt][1][v] + bg[1],
                       acc[mt][2][v] + bg[2], acc[mt][3][v] + bg[3],
                       acc[mt][4][v] + bg[4],
                       rb + v, n, d, jn, false, c_prev, A_out, c_out, out,
                       wp, bp, write_next, l15, row_base);
            }
        }
    }
}

extern "C" void kernel_launch(void* const* d_in, const int* in_sizes, int n_in,
                              void* d_out, int out_size, void* d_ws, size_t ws_size,
                              hipStream_t stream)
{
    const int*   tokens = (const int*)  d_in[0];
    const float* emb    = (const float*)d_in[1];
    const float* Wx     = (const float*)d_in[2];
    const float* Ul     = (const float*)d_in[3];
    const float* Ur     = (const float*)d_in[4];
    const float* b      = (const float*)d_in[5];
    const float* Wp     = (const float*)d_in[6];
    const float* bp     = (const float*)d_in[7];
    float* out = (float*)d_out;

    // workspace carve (~62.7 MB)
    uint8_t* w = (uint8_t*)d_ws;
    uint16_t* AP0 = (uint16_t*)w;  w += (size_t)1024 * 8  * 1024 * 2;  // 16.78 MB
    uint16_t* AP1 = (uint16_t*)w;  w += (size_t)512  * 16 * 1024 * 2;  // 16.78 MB
    float*    c0  = (float*)w;     w += (size_t)16384 * 256 * 4;       // 16.78 MB
    float*    c1  = (float*)w;     w += (size_t)8192  * 256 * 4;       //  8.39 MB
    uint16_t* BxH = (uint16_t*)w;  w += (size_t)80 * 8  * 512 * 2;
    uint16_t* BxL = (uint16_t*)w;  w += (size_t)80 * 8  * 512 * 2;
    uint16_t* BuH = (uint16_t*)w;  w += (size_t)80 * 16 * 512 * 2;
    uint16_t* BuL = (uint16_t*)w;  w += (size_t)80 * 16 * 512 * 2;

    hipMemsetAsync(out, 0, (size_t)32767 * 5 * sizeof(float), stream);

    gather_emb<<<2048, 256, 0, stream>>>(tokens, emb, AP0);
    pack_w_kernel<<<160, 256, 0, stream>>>(Wx, Wx, 8,  BxH, BxL);
    pack_w_kernel<<<320, 256, 0, stream>>>(Ul, Ur, 16, BuH, BuL);

    int off[16];
    off[0] = 0;
    for (int t = 0; t < 15; ++t) off[t + 1] = off[t] + (16384 >> t);

    // level 0: K=256 (KT=8)
    gemm_big<8, true><<<dim3(128, 8), 256, 0, stream>>>(
        AP0, BxH, BxL, b, nullptr, Wp, bp, AP1, c0, out, 16384, 1, 0);

    for (int t = 1; t <= 14; ++t) {
        int n = 16384 >> t;
        const uint16_t* Ain = (t & 1) ? AP1 : AP0;
        uint16_t* Aout      = (t & 1) ? AP0 : AP1;
        const float* cin    = (t & 1) ? c0 : c1;
        float* cout         = (t & 1) ? c1 : c0;
        int wn = (t < 14) ? 1 : 0;
        if (n >= 2048) {                 // t=1..3
            gemm_big<16, false><<<dim3(n / 128, 8), 256, 0, stream>>>(
                Ain, BuH, BuL, b, cin, Wp, bp, Aout, cout, out, n, wn, off[t]);
        } else {                         // t=4..14
            int gx = (n + 31) / 32;
            gemm_ksplit<<<dim3(gx, 16), 256, 0, stream>>>(
                Ain, BuH, BuL, b, cin, Wp, bp, Aout, cout, out, n, wn, off[t]);
        }
    }
}